// Round 6
// baseline (326.456 us; speedup 1.0000x reference)
//
#include <hip/hip_runtime.h>
#include <math.h>

// Problem constants
#define BS    2048            // batch
#define NROW  4096            // B*V = N
#define EDIM  256
#define INVT  (1.0f/0.07f)
#define NBLK  1024            // all co-resident: 4 blocks/CU (LDS 32KB -> 5/CU cap,
                              // 16 waves/CU <= 32, VGPR ~150 <= 512) -- spin barrier safe

typedef float  float4v __attribute__((ext_vector_type(4)));
typedef short  short8v __attribute__((ext_vector_type(8)));

static __device__ __forceinline__ unsigned short f2bf(float x) {
    // round-to-nearest-even f32 -> bf16 (inputs are finite)
    unsigned u = __builtin_bit_cast(unsigned, x);
    u += 0x7fffu + ((u >> 16) & 1u);
    return (unsigned short)(u >> 16);
}

static __device__ __forceinline__ float agent_loadf(const float* p) {
    return __hip_atomic_load(p, __ATOMIC_RELAXED, __HIP_MEMORY_SCOPE_AGENT);
}
static __device__ __forceinline__ unsigned agent_loadu(const unsigned* p) {
    return __hip_atomic_load(p, __ATOMIC_RELAXED, __HIP_MEMORY_SCOPE_AGENT);
}

static __device__ __forceinline__ void gload_lds16(const void* g, void* l) {
    __builtin_amdgcn_global_load_lds(
        (const __attribute__((address_space(1))) unsigned int*)g,
        (__attribute__((address_space(3))) unsigned int*)l, 16, 0, 0);
}

// ============================================================================
// Fused kernel: prep (normalize+bits) -> grid barrier -> pipelined MFMA main
// -> per-i-group finalize -> last finalizer writes out[0].
//
// Main loop is the AITER-style pipeline the m97 2-barrier structure can't
// express: raw s_barrier with per-thread s_waitcnt vmcnt(4) so the next
// sub-tile's global_load_lds stay in flight ACROSS the barrier.  Per-thread
// vm ledger: prologue = 8 outstanding (stages 0,1 x 4 loads); steady state:
// wait to 4 (stage s done, s+1 in flight), compute, lgkm-drain barrier,
// issue 4 for stage s+2.  vmcnt retires in issue order, and all register-def
// loads (A-frags, bits) are hoisted before the prologue, so the counts hold.
// ============================================================================
__global__ __launch_bounds__(256, 4) void fused_kernel(
    const float* __restrict__ feat, const float* __restrict__ labels,
    unsigned short* __restrict__ fnb, unsigned* __restrict__ bits,
    float* __restrict__ S, float* __restrict__ Num, float* __restrict__ Cnt,
    float* __restrict__ red, unsigned* __restrict__ done,
    unsigned* __restrict__ cnt_bx, unsigned* __restrict__ arrive,
    float* __restrict__ out) {

    __shared__ unsigned short shB[2][32 * 256];   // 2 x 16 KiB, swizzled granules

    const int tid  = threadIdx.x;
    const int lane = tid & 63;
    const int wave = tid >> 6;
    const int quad = lane >> 4;
    const int ml   = lane & 15;
    const int bx   = blockIdx.x;

    // ---------------- Phase A: normalize 4 rows + 2 label bitmasks ----------
    {
        const int rr = bx * 4 + wave;             // 0..4095
        const int b = rr & (BS - 1), v = rr >> 11;
        float4 x = *(const float4*)(feat + (size_t)b * 512 + (size_t)v * 256 + lane * 4);
        float ss = x.x * x.x + x.y * x.y + x.z * x.z + x.w * x.w;
#pragma unroll
        for (int off = 32; off > 0; off >>= 1)
            ss += __shfl_xor(ss, off, 64);
        float inv = 1.0f / fmaxf(sqrtf(ss), 1e-12f);
        unsigned short o0 = f2bf(x.x * inv), o1 = f2bf(x.y * inv);
        unsigned short o2 = f2bf(x.z * inv), o3 = f2bf(x.w * inv);
        uint2 pk;
        pk.x = (unsigned)o0 | ((unsigned)o1 << 16);
        pk.y = (unsigned)o2 | ((unsigned)o3 << 16);
        ((uint2*)(fnb + (size_t)rr * EDIM))[lane] = pk;
        if (tid < 2) {
            int id = bx * 2 + tid;
            unsigned bb = 0;
#pragma unroll
            for (int d = 0; d < 10; ++d)
                bb |= (labels[id * 10 + d] != 0.0f ? 1u : 0u) << d;
            bits[id] = bb;
        }
    }

    // ---------------- grid barrier (all blocks co-resident) -----------------
    __threadfence();                 // device-scope release of fnb/bits stores
    __syncthreads();
    if (tid == 0) {
        atomicAdd(arrive, 1u);       // device-scope RMW
        while (agent_loadu(arrive) < NBLK) __builtin_amdgcn_s_sleep(8);
    }
    __syncthreads();
    __builtin_amdgcn_fence(__ATOMIC_ACQUIRE, "agent");   // inv stale L1/L2

    // ---------------- Phase B: pipelined MFMA main --------------------------
    const int ig   = bx >> 4;                 // 64 i-groups of 64 rows
    const int i0   = ig * 64 + wave * 16;
    const int jc0  = (bx & 15) * 256;         // 16 j-chunks of 256
    const int xr   = ml & 7;

    // A fragments: af[h][kk], 8 x short8 = 32 VGPRs (rows i0..i0+15)
    short8v af[4][2];
    {
        const unsigned short* ap = fnb + (size_t)(i0 + ml) * EDIM + quad * 8;
#pragma unroll
        for (int h = 0; h < 4; ++h)
#pragma unroll
            for (int kk = 0; kk < 2; ++kk)
                af[h][kk] = *(const short8v*)(ap + h * 64 + kk * 32);
    }
    unsigned ibr[4];
#pragma unroll
    for (int r = 0; r < 4; ++r)
        ibr[r] = bits[(i0 + quad * 4 + r) & (BS - 1)];
    unsigned jbr[16];                          // [sub-tile s][js] = [s*2+js]
#pragma unroll
    for (int s2 = 0; s2 < 16; ++s2)
        jbr[s2] = bits[(jc0 + s2 * 16 + ml) & (BS - 1)];

    float    Sp[4][4] = {};
    float    np[4] = {};
    unsigned cpk[4] = {};   // per row: 4 x 8-bit argmax-head counts (max 16)

    // stage s (32 j-rows, 16 KiB) -> buffer p; 4 x 16B loads per thread.
    // XOR-granule swizzle: LDS[row][g] = global[row][g ^ (row&7)] keeps the
    // staging dest linear (uniform + lane*16) and frag reads ~conflict-free.
#define ISSUE_STAGE(s_, p_)                                                     \
    {                                                                           \
        const int j0s = jc0 + (s_) * 32;                                        \
        _Pragma("unroll")                                                       \
        for (int q = 0; q < 4; ++q) {                                           \
            int G = tid + 256 * q;                                              \
            int row = G >> 5, gc = G & 31;                                      \
            gload_lds16(fnb + (size_t)(j0s + row) * EDIM + ((gc ^ (row & 7)) * 8), \
                        &shB[p_][G * 8]);                                       \
        }                                                                       \
    }

    ISSUE_STAGE(0, 0)
    ISSUE_STAGE(1, 1)

#pragma unroll
    for (int s = 0; s < 8; ++s) {
        const int p = s & 1;
        // stage-s data ready (own 4 oldest loads done; s+1's stay in flight)
        if (s < 7) asm volatile("s_waitcnt vmcnt(4)\n\ts_barrier" ::: "memory");
        else       asm volatile("s_waitcnt vmcnt(0)\n\ts_barrier" ::: "memory");

        const int j0 = jc0 + s * 32;
        float4v dacc[2][4];
#pragma unroll
        for (int js = 0; js < 2; ++js)
#pragma unroll
            for (int h = 0; h < 4; ++h)
                dacc[js][h] = (float4v){0.f, 0.f, 0.f, 0.f};

#pragma unroll
        for (int h = 0; h < 4; ++h)
#pragma unroll
            for (int kk = 0; kk < 2; ++kk) {
                const int c = h * 8 + kk * 4 + quad;
                short8v b0 = *(const short8v*)(&shB[p][((ml) * 32 + (c ^ xr)) * 8]);
                short8v b1 = *(const short8v*)(&shB[p][((16 + ml) * 32 + (c ^ xr)) * 8]);
                dacc[0][h] = __builtin_amdgcn_mfma_f32_16x16x32_bf16(af[h][kk], b0, dacc[0][h], 0, 0, 0);
                dacc[1][h] = __builtin_amdgcn_mfma_f32_16x16x32_bf16(af[h][kk], b1, dacc[1][h], 0, 0, 0);
            }

        // epilogue: 8 (i,j) pairs per lane, 4 heads each
#pragma unroll
        for (int r = 0; r < 4; ++r) {
            const int i = i0 + quad * 4 + r;
            const unsigned ibit = ibr[r];
#pragma unroll
            for (int js = 0; js < 2; ++js) {
                const int j = j0 + js * 16 + ml;
                const float d0 = dacc[js][0][r];
                const float d1 = dacc[js][1][r];
                const float d2 = dacc[js][2][r];
                const float d3 = dacc[js][3][r];
                float bd = d0; int bh = 0;
                if (d1 > bd) { bd = d1; bh = 1; }
                if (d2 > bd) { bd = d2; bh = 2; }
                if (d3 > bd) { bd = d3; bh = 3; }
                const bool off = (i != j);
                const float e0 = __expf(fmaf(d0, INVT, -INVT));
                const float e1 = __expf(fmaf(d1, INVT, -INVT));
                const float e2 = __expf(fmaf(d2, INVT, -INVT));
                const float e3 = __expf(fmaf(d3, INVT, -INVT));
                if (off) {
                    Sp[r][0] += e0; Sp[r][1] += e1; Sp[r][2] += e2; Sp[r][3] += e3;
                }
                if (off && (ibit & jbr[s * 2 + js])) {
                    np[r] += bd;              // raw dot; * INVT at flush
                    cpk[r] += 1u << (bh * 8);
                }
            }
        }

        // readers done with buf p (own LDS queue drained; all at barrier)
        asm volatile("s_waitcnt lgkmcnt(0)\n\ts_barrier" ::: "memory");
        if (s + 2 < 8) ISSUE_STAGE(s + 2, p)
    }
#undef ISSUE_STAGE

    // ---- flush: reduce 16 lanes sharing each row, one atomic per value ----
#pragma unroll
    for (int r = 0; r < 4; ++r) {
        const int i = i0 + quad * 4 + r;
        float v[9];
        v[0] = np[r];
#pragma unroll
        for (int h = 0; h < 4; ++h) v[1 + h] = Sp[r][h];
#pragma unroll
        for (int h = 0; h < 4; ++h) v[5 + h] = (float)((cpk[r] >> (8 * h)) & 255u);
#pragma unroll
        for (int k = 0; k < 9; ++k) {
            float x = v[k];
            x += __shfl_xor(x, 1, 64);
            x += __shfl_xor(x, 2, 64);
            x += __shfl_xor(x, 4, 64);
            x += __shfl_xor(x, 8, 64);
            v[k] = x;
        }
        if (ml == 0) {
            atomicAdd(&Num[i], v[0] * INVT);
#pragma unroll
            for (int h = 0; h < 4; ++h) atomicAdd(&S[i * 4 + h], v[1 + h]);
#pragma unroll
            for (int h = 0; h < 4; ++h) atomicAdd(&Cnt[i * 4 + h], v[5 + h]);
        }
    }

    // ---- Phase C: last of 16 j-chunk contributors finalizes its 64 rows ----
    __shared__ unsigned flag;
    __threadfence();
    __syncthreads();
    if (tid == 0) flag = atomicAdd(&cnt_bx[ig], 1u);
    __syncthreads();
    if (flag == 15u && tid < 64) {
        const int i = ig * 64 + tid;
        float c = 0.f;
        float numr = agent_loadf(&Num[i]);
#pragma unroll
        for (int h = 0; h < 4; ++h) {
            float sh = agent_loadf(&S[i * 4 + h]);
            float ch = agent_loadf(&Cnt[i * 4 + h]);
            numr -= ch * (INVT + logf(sh));
            c += ch;
        }
        float ls = 0.f, lc = 0.f;
        if (c > 0.f) { ls = -(numr / c); lc = 1.f; }
#pragma unroll
        for (int off = 1; off < 64; off <<= 1) {
            ls += __shfl_xor(ls, off, 64);
            lc += __shfl_xor(lc, off, 64);
        }
        if (tid == 0) {
            atomicAdd(&red[0], ls);
            atomicAdd(&red[1], lc);
            __threadfence();
            if (atomicAdd(done, 1u) == 63u) {
                float sm = agent_loadf(&red[0]);
                float cc = agent_loadf(&red[1]);
                out[0] = sm / cc;
            }
        }
    }
}

extern "C" void kernel_launch(void* const* d_in, const int* in_sizes, int n_in,
                              void* d_out, int out_size, void* d_ws, size_t ws_size,
                              hipStream_t stream) {
    const float* feat = (const float*)d_in[0];    // (2048, 2, 256) f32
    const float* labels = (const float*)d_in[1];  // (2048, 10) f32
    float* out = (float*)d_out;

    char* ws = (char*)d_ws;
    unsigned short* fnb = (unsigned short*)ws;                     // N*E bf16 (2 MB)
    float* S = (float*)(ws + (size_t)NROW * EDIM * sizeof(unsigned short));
    float* Num = S + NROW * 4;                // N
    float* Cnt = Num + NROW;                  // N*4
    float* red = Cnt + NROW * 4;              // [2] sum, count
    unsigned* done = (unsigned*)(red + 2);    // finalize counter
    unsigned* cnt_bx = done + 1;              // per-i-group contributor counters [64]
    unsigned* arrive = cnt_bx + 64;           // grid-barrier arrival counter
    unsigned* bits = arrive + 1;              // BS label bitmasks (written pre-barrier)

    // zero S/Num/Cnt/red/done/cnt_bx/arrive in one contiguous memset
    size_t zbytes = (size_t)(NROW * 9 + 2) * sizeof(float) + (1 + 64 + 1) * sizeof(unsigned);
    (void)hipMemsetAsync(S, 0, zbytes, stream);

    fused_kernel<<<NBLK, 256, 0, stream>>>(feat, labels, fnb, bits, S, Num, Cnt,
                                           red, done, cnt_bx, arrive, out);
}

// Round 7
// 169.118 us; speedup vs baseline: 1.9303x; 1.9303x over previous
//
#include <hip/hip_runtime.h>
#include <math.h>

// Problem constants
#define BS    2048            // batch
#define NROW  4096            // B*V = N
#define EDIM  256
#define INVT  (1.0f/0.07f)

typedef float  float4v __attribute__((ext_vector_type(4)));
typedef short  short8v __attribute__((ext_vector_type(8)));

static __device__ __forceinline__ unsigned short f2bf(float x) {
    // round-to-nearest-even f32 -> bf16 (inputs are finite)
    unsigned u = __builtin_bit_cast(unsigned, x);
    u += 0x7fffu + ((u >> 16) & 1u);
    return (unsigned short)(u >> 16);
}

static __device__ __forceinline__ float agent_loadf(const float* p) {
    return __hip_atomic_load(p, __ATOMIC_RELAXED, __HIP_MEMORY_SCOPE_AGENT);
}

static __device__ __forceinline__ void gload_lds16(const void* g, void* l) {
    __builtin_amdgcn_global_load_lds(
        (const __attribute__((address_space(1))) unsigned int*)g,
        (__attribute__((address_space(3))) unsigned int*)l, 16, 0, 0);
}

// ---------------- prep kernel: normalize + label bits (R3-proven) -----------
__global__ void prep_kernel(const float* __restrict__ feat, const float* __restrict__ labels,
                            unsigned short* __restrict__ fnb, unsigned* __restrict__ bits) {
    const int b = blockIdx.x, t = threadIdx.x;
    if (b < NROW) {
        int bb = b & (BS - 1);
        int v = b >> 11;
        float x = feat[(size_t)bb * (2 * EDIM) + (size_t)v * EDIM + t];
        float ss = x * x;
#pragma unroll
        for (int off = 32; off > 0; off >>= 1)
            ss += __shfl_xor(ss, off, 64);
        float nrm = fmaxf(sqrtf(ss), 1e-12f);
        fnb[(size_t)b * EDIM + t] = f2bf(x / nrm);
    } else {
        int g = (b - NROW) * 256 + t;   // 0..2047
        unsigned bb = 0;
#pragma unroll
        for (int d = 0; d < 10; ++d)
            bb |= (labels[g * 10 + d] != 0.0f ? 1u : 0u) << d;
        bits[g] = bb;
    }
}

// ============================================================================
// Main kernel: AITER-style pipelined MFMA loop + in-kernel finalization.
// grid (64 i-groups, 16 j-chunks), block 256 = 4 waves, launch_bounds(256,3)
// -> 170-reg/wave cap (NO spills; R6's (256,4)=128 cap spilled catastrophically).
// Wave w: i-rows [ig*64 + w*16, +16), j-chunk [by*256, +256) as 8 stages of 32.
// Raw s_barrier with per-thread s_waitcnt vmcnt(4): next stage's 4
// global_load_lds stay in flight ACROSS the barrier.  Ledger: prologue = 8
// outstanding (stages 0,1); steady: wait to 4 (stage s drained -- its 4 loads
// are the oldest >=8 outstanding, FIFO retire => safe vs any extra VMEM),
// compute, lgkm-drain barrier (readers done), issue stage s+2.
// XOR-granule swizzle keeps staging dest linear + frag reads 2-way-free.
// C/D layout (m89/m91): col = lane&15, row = (lane>>4)*4 + reg.
// ============================================================================
__global__ __launch_bounds__(256, 3) void main_kernel(
    const unsigned short* __restrict__ fnb, const unsigned* __restrict__ bits,
    float* __restrict__ S, float* __restrict__ Num, float* __restrict__ Cnt,
    float* __restrict__ red, unsigned* __restrict__ done,
    unsigned* __restrict__ cnt_bx, float* __restrict__ out) {

    __shared__ unsigned short shB[2][32 * 256];   // 2 x 16 KiB, swizzled granules

    const int tid  = threadIdx.x;
    const int lane = tid & 63;
    const int wave = tid >> 6;
    const int quad = lane >> 4;
    const int ml   = lane & 15;
    const int ig   = blockIdx.x;              // 64 i-groups of 64 rows
    const int i0   = ig * 64 + wave * 16;
    const int jc0  = blockIdx.y * 256;        // 16 j-chunks of 256
    const int xr   = ml & 7;

    // A fragments: af[h][kk], 8 x short8 = 32 VGPRs (rows i0..i0+15)
    short8v af[4][2];
    {
        const unsigned short* ap = fnb + (size_t)(i0 + ml) * EDIM + quad * 8;
#pragma unroll
        for (int h = 0; h < 4; ++h)
#pragma unroll
            for (int kk = 0; kk < 2; ++kk)
                af[h][kk] = *(const short8v*)(ap + h * 64 + kk * 32);
    }
    unsigned ibr[4];
#pragma unroll
    for (int r = 0; r < 4; ++r)
        ibr[r] = bits[(i0 + quad * 4 + r) & (BS - 1)];
    unsigned jbr[16];                          // [stage s][js] = [s*2+js]
#pragma unroll
    for (int s2 = 0; s2 < 16; ++s2)
        jbr[s2] = bits[(jc0 + s2 * 16 + ml) & (BS - 1)];

    float    Sp[4][4] = {};
    float    np[4] = {};
    unsigned cpk[4] = {};   // per row: 4 x 8-bit argmax-head counts (max 16)

    // stage s (32 j-rows, 16 KiB) -> buffer p; 4 x 16B loads per thread.
#define ISSUE_STAGE(s_, p_)                                                     \
    {                                                                           \
        const int j0s = jc0 + (s_) * 32;                                        \
        _Pragma("unroll")                                                       \
        for (int q = 0; q < 4; ++q) {                                           \
            int G = tid + 256 * q;                                              \
            int row = G >> 5, gc = G & 31;                                      \
            gload_lds16(fnb + (size_t)(j0s + row) * EDIM + ((gc ^ (row & 7)) * 8), \
                        &shB[p_][G * 8]);                                       \
        }                                                                       \
    }

    ISSUE_STAGE(0, 0)
    ISSUE_STAGE(1, 1)

#pragma unroll
    for (int s = 0; s < 8; ++s) {
        const int p = s & 1;
        // stage-s data ready (own 4 oldest loads done; s+1's stay in flight)
        if (s < 7) asm volatile("s_waitcnt vmcnt(4)\n\ts_barrier" ::: "memory");
        else       asm volatile("s_waitcnt vmcnt(0)\n\ts_barrier" ::: "memory");

        const int j0 = jc0 + s * 32;
        float4v dacc[2][4];
#pragma unroll
        for (int js = 0; js < 2; ++js)
#pragma unroll
            for (int h = 0; h < 4; ++h)
                dacc[js][h] = (float4v){0.f, 0.f, 0.f, 0.f};

#pragma unroll
        for (int h = 0; h < 4; ++h)
#pragma unroll
            for (int kk = 0; kk < 2; ++kk) {
                const int c = h * 8 + kk * 4 + quad;
                short8v b0 = *(const short8v*)(&shB[p][((ml) * 32 + (c ^ xr)) * 8]);
                short8v b1 = *(const short8v*)(&shB[p][((16 + ml) * 32 + (c ^ xr)) * 8]);
                dacc[0][h] = __builtin_amdgcn_mfma_f32_16x16x32_bf16(af[h][kk], b0, dacc[0][h], 0, 0, 0);
                dacc[1][h] = __builtin_amdgcn_mfma_f32_16x16x32_bf16(af[h][kk], b1, dacc[1][h], 0, 0, 0);
            }

        // epilogue: 8 (i,j) pairs per lane, 4 heads each
#pragma unroll
        for (int r = 0; r < 4; ++r) {
            const int i = i0 + quad * 4 + r;
            const unsigned ibit = ibr[r];
#pragma unroll
            for (int js = 0; js < 2; ++js) {
                const int j = j0 + js * 16 + ml;
                const float d0 = dacc[js][0][r];
                const float d1 = dacc[js][1][r];
                const float d2 = dacc[js][2][r];
                const float d3 = dacc[js][3][r];
                float bd = d0; int bh = 0;
                if (d1 > bd) { bd = d1; bh = 1; }
                if (d2 > bd) { bd = d2; bh = 2; }
                if (d3 > bd) { bd = d3; bh = 3; }
                const bool off = (i != j);
                const float e0 = __expf(fmaf(d0, INVT, -INVT));
                const float e1 = __expf(fmaf(d1, INVT, -INVT));
                const float e2 = __expf(fmaf(d2, INVT, -INVT));
                const float e3 = __expf(fmaf(d3, INVT, -INVT));
                if (off) {
                    Sp[r][0] += e0; Sp[r][1] += e1; Sp[r][2] += e2; Sp[r][3] += e3;
                }
                if (off && (ibit & jbr[s * 2 + js])) {
                    np[r] += bd;              // raw dot; * INVT at flush
                    cpk[r] += 1u << (bh * 8);
                }
            }
        }

        // readers done with buf p (own LDS queue drained; all at barrier)
        asm volatile("s_waitcnt lgkmcnt(0)\n\ts_barrier" ::: "memory");
        if (s + 2 < 8) ISSUE_STAGE(s + 2, p)
    }
#undef ISSUE_STAGE

    // ---- flush: reduce 16 lanes sharing each row, one atomic per value ----
#pragma unroll
    for (int r = 0; r < 4; ++r) {
        const int i = i0 + quad * 4 + r;
        float v[9];
        v[0] = np[r];
#pragma unroll
        for (int h = 0; h < 4; ++h) v[1 + h] = Sp[r][h];
#pragma unroll
        for (int h = 0; h < 4; ++h) v[5 + h] = (float)((cpk[r] >> (8 * h)) & 255u);
#pragma unroll
        for (int k = 0; k < 9; ++k) {
            float x = v[k];
            x += __shfl_xor(x, 1, 64);
            x += __shfl_xor(x, 2, 64);
            x += __shfl_xor(x, 4, 64);
            x += __shfl_xor(x, 8, 64);
            v[k] = x;
        }
        if (ml == 0) {
            atomicAdd(&Num[i], v[0] * INVT);
#pragma unroll
            for (int h = 0; h < 4; ++h) atomicAdd(&S[i * 4 + h], v[1 + h]);
#pragma unroll
            for (int h = 0; h < 4; ++h) atomicAdd(&Cnt[i * 4 + h], v[5 + h]);
        }
    }

    // ---- finalize: last of 16 j-chunk contributors handles its 64 rows ----
    __shared__ unsigned flag;
    __threadfence();
    __syncthreads();
    if (tid == 0) flag = atomicAdd(&cnt_bx[ig], 1u);
    __syncthreads();
    if (flag == 15u && tid < 64) {
        const int i = ig * 64 + tid;
        float c = 0.f;
        float numr = agent_loadf(&Num[i]);
#pragma unroll
        for (int h = 0; h < 4; ++h) {
            float sh = agent_loadf(&S[i * 4 + h]);
            float ch = agent_loadf(&Cnt[i * 4 + h]);
            numr -= ch * (INVT + logf(sh));
            c += ch;
        }
        float ls = 0.f, lc = 0.f;
        if (c > 0.f) { ls = -(numr / c); lc = 1.f; }
#pragma unroll
        for (int off = 1; off < 64; off <<= 1) {
            ls += __shfl_xor(ls, off, 64);
            lc += __shfl_xor(lc, off, 64);
        }
        if (tid == 0) {
            atomicAdd(&red[0], ls);
            atomicAdd(&red[1], lc);
            __threadfence();
            if (atomicAdd(done, 1u) == 63u) {
                float sm = agent_loadf(&red[0]);
                float cc = agent_loadf(&red[1]);
                out[0] = sm / cc;
            }
        }
    }
}

extern "C" void kernel_launch(void* const* d_in, const int* in_sizes, int n_in,
                              void* d_out, int out_size, void* d_ws, size_t ws_size,
                              hipStream_t stream) {
    const float* feat = (const float*)d_in[0];    // (2048, 2, 256) f32
    const float* labels = (const float*)d_in[1];  // (2048, 10) f32
    float* out = (float*)d_out;

    char* ws = (char*)d_ws;
    unsigned short* fnb = (unsigned short*)ws;                     // N*E bf16 (2 MB)
    float* S = (float*)(ws + (size_t)NROW * EDIM * sizeof(unsigned short));
    float* Num = S + NROW * 4;                // N
    float* Cnt = Num + NROW;                  // N*4
    float* red = Cnt + NROW * 4;              // [2] sum, count
    unsigned* done = (unsigned*)(red + 2);    // finalize counter
    unsigned* cnt_bx = done + 1;              // per-i-group contributor counters [64]
    unsigned* bits = cnt_bx + 64;             // BS label bitmasks

    // zero S/Num/Cnt/red/done/cnt_bx in one contiguous memset
    size_t zbytes = (size_t)(NROW * 9 + 2) * sizeof(float) + (1 + 64) * sizeof(unsigned);
    (void)hipMemsetAsync(S, 0, zbytes, stream);

    prep_kernel<<<NROW + 8, 256, 0, stream>>>(feat, labels, fnb, bits);
    main_kernel<<<dim3(64, 16), 256, 0, stream>>>(fnb, bits, S, Num, Cnt,
                                                  red, done, cnt_bx, out);
}